// Round 1
// baseline (82.407 us; speedup 1.0000x reference)
//
#include <hip/hip_runtime.h>

#define NSTEPS 10
#define D_IN   14400
#define BATCH  256
#define KNN_K  25

// ---- transpose the last-step slice: in (B, NSTEPS, D_IN) -> out (D_IN, B) ----
__global__ void slice_transpose(const float* __restrict__ in, float* __restrict__ out) {
    __shared__ float tile[64][65];                 // +1 pad: conflict-free both ways
    const int d0 = blockIdx.x * 64;
    const int b0 = blockIdx.y * 64;
    const int tx = threadIdx.x;                    // 0..63
    const int ty = threadIdx.y;                    // 0..3
#pragma unroll
    for (int i = 0; i < 16; ++i) {
        const int bl = ty * 16 + i;
        tile[bl][tx] = in[(size_t)(b0 + bl) * (NSTEPS * D_IN) + (size_t)(NSTEPS - 1) * D_IN + d0 + tx];
    }
    __syncthreads();
#pragma unroll
    for (int i = 0; i < 16; ++i) {
        const int dl = ty * 16 + i;
        out[(size_t)(d0 + dl) * BATCH + b0 + tx] = tile[tx][dl];
    }
}

// ---- one LCN layer: y[d][b] = bias[d] + sum_k x[knn[d][k]][b] * w[d][k] ----
// one 64-thread block per output neuron d; each lane handles 4 batches (float4)
__global__ void lcn_layer(const float* __restrict__ xp, const int* __restrict__ knn,
                          const float* __restrict__ w, const float* __restrict__ bias,
                          float* __restrict__ y) {
    const int d    = blockIdx.x;                   // block-uniform -> scalar knn/w loads
    const int lane = threadIdx.x;                  // 0..63
    const int b    = lane * 4;

    const int*   kp = knn + (size_t)d * KNN_K;
    const float* wp = w   + (size_t)d * KNN_K;

    const float bv = bias[d];
    float4 acc;
    acc.x = bv; acc.y = bv; acc.z = bv; acc.w = bv;

#pragma unroll
    for (int k = 0; k < KNN_K; ++k) {
        const int   idx = kp[k];
        const float wk  = wp[k];
        const float4 v  = *reinterpret_cast<const float4*>(xp + (size_t)idx * BATCH + b);
        acc.x += v.x * wk;
        acc.y += v.y * wk;
        acc.z += v.z * wk;
        acc.w += v.w * wk;
    }
    *reinterpret_cast<float4*>(y + (size_t)d * BATCH + b) = acc;
}

// ---- final fc: out[b][o] = fc_b[o] + sum_d x[d][b] * fc_w[o][d]  (o = 0,1; d < 450) ----
__global__ void fc_kernel(const float* __restrict__ x, const float* __restrict__ fw,
                          const float* __restrict__ fb, float* __restrict__ out) {
    const int b = threadIdx.x;                     // 256 threads, one block
    float a0 = fb[0];
    float a1 = fb[1];
#pragma unroll 5
    for (int d = 0; d < 450; ++d) {
        const float xv = x[(size_t)d * BATCH + b]; // coalesced across b
        a0 += xv * fw[d];
        a1 += xv * fw[450 + d];
    }
    out[b * 2 + 0] = a0;
    out[b * 2 + 1] = a1;
}

extern "C" void kernel_launch(void* const* d_in, const int* in_sizes, int n_in,
                              void* d_out, int out_size, void* d_ws, size_t ws_size,
                              hipStream_t stream) {
    // dict order: input, (knn0,w0,b0), (knn1,w1,b1), ..., (knn4,w4,b4), fc_w, fc_b
    const float* input = (const float*)d_in[0];
    const int*   knn[5];
    const float* w[5];
    const float* bias[5];
    for (int i = 0; i < 5; ++i) {
        knn[i]  = (const int*)  d_in[1 + 3 * i];
        w[i]    = (const float*)d_in[2 + 3 * i];
        bias[i] = (const float*)d_in[3 + 3 * i];
    }
    const float* fc_w = (const float*)d_in[16];
    const float* fc_b = (const float*)d_in[17];
    float* out = (float*)d_out;

    // workspace ping-pong: A holds x0 (14400x256), B holds up to 7200x256
    float* A = (float*)d_ws;
    float* B = A + (size_t)D_IN * BATCH;

    // 1) slice + transpose to feature-major
    slice_transpose<<<dim3(D_IN / 64, BATCH / 64), dim3(64, 4), 0, stream>>>(input, A);

    // 2) five LCN layers
    const int dims_out[5] = {7200, 3600, 1800, 900, 450};
    for (int i = 0; i < 5; ++i) {
        const float* src = (i & 1) ? B : A;
        float*       dst = (i & 1) ? A : B;
        lcn_layer<<<dims_out[i], 64, 0, stream>>>(src, knn[i], w[i], bias[i], dst);
    }
    // x5 (450 x 256) ends up in B

    // 3) fc head
    fc_kernel<<<1, BATCH, 0, stream>>>(B, fc_w, fc_b, out);
}

// Round 2
// 65.649 us; speedup vs baseline: 1.2553x; 1.2553x over previous
//
#include <hip/hip_runtime.h>

#define NSTEPS 10
#define D_IN   14400
#define BATCH  256
#define KNN_K  25

// layer output dims: 7200, 3600, 1800, 900, 450; cumulative neuron offsets:
//   L0:0  L1:7200  L2:10800  L3:12600  L4:13500  total:13950
#define NTOT   13950
#define ROWP   26          // pairs per packed row (25 + 1 pad), 208 B, 16B-aligned
#define ROWI   (ROWP * 2)  // ints per packed row = 52

// ---- prologue: repack knn+w into interleaved (idx, w_bits) rows of 26 pairs ----
__global__ void repack_knnw(const int* __restrict__ k0, const float* __restrict__ w0,
                            const int* __restrict__ k1, const float* __restrict__ w1,
                            const int* __restrict__ k2, const float* __restrict__ w2,
                            const int* __restrict__ k3, const float* __restrict__ w3,
                            const int* __restrict__ k4, const float* __restrict__ w4,
                            int* __restrict__ outp)
{
    const int p  = blockIdx.x * 256 + threadIdx.x;   // pair id
    const int NP = NTOT * ROWP;
    if (p >= NP) return;
    const int n = p / ROWP;
    const int k = p - n * ROWP;
    const int* kp; const float* wp; int dl;
    if      (n < 7200)  { kp = k0; wp = w0; dl = n; }
    else if (n < 10800) { kp = k1; wp = w1; dl = n - 7200; }
    else if (n < 12600) { kp = k2; wp = w2; dl = n - 10800; }
    else if (n < 13500) { kp = k3; wp = w3; dl = n - 12600; }
    else                { kp = k4; wp = w4; dl = n - 13500; }
    int idx = 0; float wv = 0.0f;
    if (k < KNN_K) { idx = kp[dl * KNN_K + k]; wv = wp[dl * KNN_K + k]; }
    outp[2 * p]     = idx;
    outp[2 * p + 1] = __float_as_int(wv);
}

// ---- fused network: one block = 2 batches, all activations in LDS ----
__global__ __launch_bounds__(512, 2)
void lcn_fused(const float* __restrict__ input,
               const int*   __restrict__ pk,
               const float* __restrict__ bias0, const float* __restrict__ bias1,
               const float* __restrict__ bias2, const float* __restrict__ bias3,
               const float* __restrict__ bias4,
               const float* __restrict__ fc_w,  const float* __restrict__ fc_b,
               float* __restrict__ out)
{
    __shared__ __align__(16) float xa[2 * D_IN];     // 115.2 KB
    float2* const x2 = (float2*)xa;                  // 14400 float2 (batch-interleaved)
    const int tid = threadIdx.x;
    const int bp  = blockIdx.x * 2;                  // first batch of the pair

    // ---- stage the last-step input rows for both batches, interleaved ----
    {
        const float4* r0 = (const float4*)(input + ((size_t)bp       * NSTEPS + (NSTEPS - 1)) * D_IN);
        const float4* r1 = (const float4*)(input + ((size_t)(bp + 1) * NSTEPS + (NSTEPS - 1)) * D_IN);
        for (int i = tid; i < D_IN / 4; i += 512) {
            float4 u = r0[i], v = r1[i];
            float2* dst = x2 + i * 4;
            dst[0] = make_float2(u.x, v.x);
            dst[1] = make_float2(u.y, v.y);
            dst[2] = make_float2(u.z, v.z);
            dst[3] = make_float2(u.w, v.w);
        }
    }
    __syncthreads();

    // ---- layer 0: 14400 -> 7200. Reads ALL of xa, so stage output in registers. ----
    float a0[15], a1[15];
#pragma unroll
    for (int i = 0; i < 15; ++i) {
        const int d = tid + i * 512;
        if (d < 7200) {
            const int4* row = (const int4*)(pk + (size_t)d * ROWI);
            int4 r[13];
#pragma unroll
            for (int q = 0; q < 13; ++q) r[q] = row[q];
            float s0 = bias0[d], s1 = s0;
#pragma unroll
            for (int q = 0; q < 13; ++q) {
                const float2 v0 = x2[r[q].x]; const float w0 = __int_as_float(r[q].y);
                const float2 v1 = x2[r[q].z]; const float w1 = __int_as_float(r[q].w);
                s0 += v0.x * w0 + v1.x * w1;
                s1 += v0.y * w0 + v1.y * w1;
            }
            a0[i] = s0; a1[i] = s1;
        }
    }
    __syncthreads();                                  // all reads of x0 done
#pragma unroll
    for (int i = 0; i < 15; ++i) {
        const int d = tid + i * 512;
        if (d < 7200) x2[d] = make_float2(a0[i], a1[i]);
    }
    __syncthreads();

    // ---- layers 1..4: ping-pong between region A (f2[0..7200)) and B (f2[7200..)) ----
    float2* const A = x2;
    float2* const B = x2 + 7200;

    // generic layer body
    auto layer = [&](const float2* __restrict__ xin, float2* __restrict__ xout,
                     const int* __restrict__ pkrow, const float* __restrict__ bias,
                     int dim) {
        for (int d = tid; d < dim; d += 512) {
            const int4* row = (const int4*)(pkrow + (size_t)d * ROWI);
            int4 r[13];
#pragma unroll
            for (int q = 0; q < 13; ++q) r[q] = row[q];
            float s0 = bias[d], s1 = s0;
#pragma unroll
            for (int q = 0; q < 13; ++q) {
                const float2 v0 = xin[r[q].x]; const float w0 = __int_as_float(r[q].y);
                const float2 v1 = xin[r[q].z]; const float w1 = __int_as_float(r[q].w);
                s0 += v0.x * w0 + v1.x * w1;
                s1 += v0.y * w0 + v1.y * w1;
            }
            xout[d] = make_float2(s0, s1);
        }
        __syncthreads();
    };

    layer(A, B, pk + (size_t)7200  * ROWI, bias1, 3600);  // B[0:3600)
    layer(B, A, pk + (size_t)10800 * ROWI, bias2, 1800);  // A[0:1800)
    layer(A, B, pk + (size_t)12600 * ROWI, bias3, 900);   // B[0:900)
    layer(B, A, pk + (size_t)13500 * ROWI, bias4, 450);   // A[0:450)

    // ---- fc head: 4 dots (2 batches x 2 outputs), one wave each ----
    const int wv   = tid >> 6;   // wave id 0..7
    const int lane = tid & 63;
    if (wv < 4) {
        const int j = wv & 1;    // batch within pair
        const int o = wv >> 1;   // output channel
        float s = 0.0f;
        for (int d = lane; d < 450; d += 64) {
            const float xv = (j == 0) ? A[d].x : A[d].y;
            s += xv * fc_w[o * 450 + d];
        }
#pragma unroll
        for (int off = 32; off > 0; off >>= 1) s += __shfl_xor(s, off);
        if (lane == 0) out[(bp + j) * 2 + o] = s + fc_b[o];
    }
}

extern "C" void kernel_launch(void* const* d_in, const int* in_sizes, int n_in,
                              void* d_out, int out_size, void* d_ws, size_t ws_size,
                              hipStream_t stream) {
    // dict order: input, (knn_i, w_i, b_i) x5, fc_w, fc_b
    const float* input = (const float*)d_in[0];
    const int*   knn[5];
    const float* w[5];
    const float* bias[5];
    for (int i = 0; i < 5; ++i) {
        knn[i]  = (const int*)  d_in[1 + 3 * i];
        w[i]    = (const float*)d_in[2 + 3 * i];
        bias[i] = (const float*)d_in[3 + 3 * i];
    }
    const float* fc_w = (const float*)d_in[16];
    const float* fc_b = (const float*)d_in[17];
    float* out = (float*)d_out;

    int* pk = (int*)d_ws;   // NTOT * 52 ints = 2.9 MB packed (idx,w) rows

    const int np = NTOT * ROWP;
    repack_knnw<<<(np + 255) / 256, 256, 0, stream>>>(
        knn[0], w[0], knn[1], w[1], knn[2], w[2], knn[3], w[3], knn[4], w[4], pk);

    lcn_fused<<<BATCH / 2, 512, 0, stream>>>(
        input, pk, bias[0], bias[1], bias[2], bias[3], bias[4], fc_w, fc_b, out);
}

// Round 3
// 37.454 us; speedup vs baseline: 2.2002x; 1.7528x over previous
//
#include <hip/hip_runtime.h>

#define NSTEPS 10
#define D_IN   14400
#define BATCH  256
#define KNN_K  25

// layer dims
#define L0D 7200
#define L1D 3600
#define L2D 1800
#define L3D 900
#define L4D 450

// 64-row groups per layer (ceil(dim/64))
#define G0 113
#define G1 57
#define G2 29
#define G3 15
#define G4 8
// uint2 slots per group = 13 pair-pairs * 64 lanes
#define SPG 832
// layer tile offsets (uint2 units)
#define O0 0
#define O1 (G0*SPG)            // 94016
#define O2 (O1 + G1*SPG)       // 141440
#define O3 (O2 + G2*SPG)       // 165568
#define O4 (O3 + G3*SPG)       // 178048
#define OTOT (O4 + G4*SPG)     // 184704

// round-to-nearest-even f32 -> bf16 bits
__device__ __forceinline__ unsigned bf16b(float x) {
    unsigned u = __float_as_uint(x);
    return (u + 0x7fffu + ((u >> 16) & 1u)) >> 16;
}

// one packed pair: u = (bf16_w << 16) | (idx << 2); act word = bf16 b0 | bf16 b1 << 16
__device__ __forceinline__ void gpair(unsigned u, const char* actb, float& s0, float& s1) {
    unsigned av = *(const unsigned*)(actb + (u & 0xffffu));
    float wf = __uint_as_float(u & 0xffff0000u);
    s0 = fmaf(__uint_as_float(av << 16),          wf, s0);
    s1 = fmaf(__uint_as_float(av & 0xffff0000u),  wf, s1);
}

// ---- prologue: build lane-major SoA weight tiles, bf16 weights, byte-shifted idx ----
__global__ void repack_tiles(const int* __restrict__ k0, const float* __restrict__ w0,
                             const int* __restrict__ k1, const float* __restrict__ w1,
                             const int* __restrict__ k2, const float* __restrict__ w2,
                             const int* __restrict__ k3, const float* __restrict__ w3,
                             const int* __restrict__ k4, const float* __restrict__ w4,
                             uint2* __restrict__ tile)
{
    int s = blockIdx.x * 256 + threadIdx.x;
    if (s >= OTOT) return;
    const int* kp; const float* wp; int dim, t;
    if      (s < O1) { kp = k0; wp = w0; dim = L0D; t = s;      }
    else if (s < O2) { kp = k1; wp = w1; dim = L1D; t = s - O1; }
    else if (s < O3) { kp = k2; wp = w2; dim = L2D; t = s - O2; }
    else if (s < O4) { kp = k3; wp = w3; dim = L3D; t = s - O3; }
    else             { kp = k4; wp = w4; dim = L4D; t = s - O4; }
    int g    = t / SPG;
    int rem  = t - g * SPG;
    int j    = rem >> 6;          // 0..12
    int lane = rem & 63;
    int r    = g * 64 + lane;
    unsigned vx = 0, vy = 0;
    if (r < dim) {
        int e0 = 2 * j, e1 = 2 * j + 1;
        if (e0 < KNN_K) vx = (bf16b(wp[r * KNN_K + e0]) << 16) | ((unsigned)kp[r * KNN_K + e0] << 2);
        if (e1 < KNN_K) vy = (bf16b(wp[r * KNN_K + e1]) << 16) | ((unsigned)kp[r * KNN_K + e1] << 2);
    }
    tile[s] = make_uint2(vx, vy);
}

// ---- layer 0: 256 blocks = 128 pairs x 2 neuron-halves; input pair staged bf16x2 in LDS ----
__global__ __launch_bounds__(512, 4)
void lcn_l0(const float* __restrict__ input, const uint2* __restrict__ tile,
            const float* __restrict__ bias0, unsigned* __restrict__ y0)
{
    __shared__ unsigned act[D_IN];          // 57.6 KB -> 2 blocks/CU
    const int tid = threadIdx.x;
    const int p   = blockIdx.x & 127;       // blocks p and p+128 share pair p (same XCD slot)
    const int h   = blockIdx.x >> 7;

    const float4* r0 = (const float4*)(input + ((size_t)(2 * p)     * NSTEPS + (NSTEPS - 1)) * D_IN);
    const float4* r1 = (const float4*)(input + ((size_t)(2 * p + 1) * NSTEPS + (NSTEPS - 1)) * D_IN);
    for (int i = tid; i < D_IN / 4; i += 512) {
        float4 a = r0[i], b = r1[i];
        uint4 wd;
        wd.x = bf16b(a.x) | (bf16b(b.x) << 16);
        wd.y = bf16b(a.y) | (bf16b(b.y) << 16);
        wd.z = bf16b(a.z) | (bf16b(b.z) << 16);
        wd.w = bf16b(a.w) | (bf16b(b.w) << 16);
        *(uint4*)(act + i * 4) = wd;
    }
    __syncthreads();
    const char* actb = (const char*)act;

    const int rbase = h ? 3584 : 0;         // 3584 = 56 groups: 64-aligned split
    const int rend  = h ? 7200 : 3584;
#pragma unroll
    for (int i = 0; i < 8; ++i) {
        int r = rbase + tid + i * 512;
        if (r < rend) {
            const uint2* tp = tile + (size_t)(r >> 6) * SPG + (r & 63);
            float s0 = bias0[r], s1 = s0;
#pragma unroll
            for (int j = 0; j < 13; ++j) {
                uint2 u = tp[j * 64];       // coalesced 512B per wave
                gpair(u.x, actb, s0, s1);
                gpair(u.y, actb, s0, s1);
            }
            y0[(size_t)p * L0D + r] = bf16b(s0) | (bf16b(s1) << 16);
        }
    }
}

// ---- one deep layer: gather from act[0:prev), reg-stage, write back in place ----
template<int DIM>
__device__ __forceinline__ void k2_layer(unsigned* act, const uint2* tile,
                                         const float* __restrict__ bias, int tid)
{
    constexpr int NI = (DIM + 1023) / 1024;
    float s0[NI], s1[NI];
    const char* actb = (const char*)act;
#pragma unroll
    for (int i = 0; i < NI; ++i) {
        int r = tid + i * 1024;
        if (r < DIM) {
            const uint2* tp = tile + (size_t)(r >> 6) * SPG + (r & 63);
            float a = bias[r], b = a;
#pragma unroll
            for (int j = 0; j < 13; ++j) {
                uint2 u = tp[j * 64];
                gpair(u.x, actb, a, b);
                gpair(u.y, actb, a, b);
            }
            s0[i] = a; s1[i] = b;
        }
    }
    __syncthreads();
#pragma unroll
    for (int i = 0; i < NI; ++i) {
        int r = tid + i * 1024;
        if (r < DIM) act[r] = bf16b(s0[i]) | (bf16b(s1[i]) << 16);
    }
    __syncthreads();
}

// ---- layers 1-4 + fc head: 128 blocks (one per pair), 1024 threads ----
__global__ __launch_bounds__(1024, 4)
void lcn_rest(const unsigned* __restrict__ y0, const uint2* __restrict__ tile,
              const float* __restrict__ bias1, const float* __restrict__ bias2,
              const float* __restrict__ bias3, const float* __restrict__ bias4,
              const float* __restrict__ fc_w,  const float* __restrict__ fc_b,
              float* __restrict__ out)
{
    __shared__ unsigned act[L0D];           // 28.8 KB
    const int tid = threadIdx.x;
    const int p   = blockIdx.x;

    const uint4* src = (const uint4*)(y0 + (size_t)p * L0D);
#pragma unroll
    for (int i = 0; i < 2; ++i) {
        int q = tid + i * 1024;
        if (q < L0D / 4) *(uint4*)(act + q * 4) = src[q];
    }
    __syncthreads();

    k2_layer<L1D>(act, tile + O1, bias1, tid);
    k2_layer<L2D>(act, tile + O2, bias2, tid);
    k2_layer<L3D>(act, tile + O3, bias3, tid);
    k2_layer<L4D>(act, tile + O4, bias4, tid);

    // fc head: 4 waves handle (batch j, out o)
    const int wv = tid >> 6, lane = tid & 63;
    if (wv < 4) {
        const int j = wv & 1, o = wv >> 1;
        float s = 0.f;
#pragma unroll
        for (int it = 0; it < 8; ++it) {
            int r = lane + it * 64;
            if (r < L4D) {
                unsigned av = act[r];
                float xv = j ? __uint_as_float(av & 0xffff0000u)
                             : __uint_as_float(av << 16);
                s += xv * fc_w[o * L4D + r];
            }
        }
#pragma unroll
        for (int off = 32; off > 0; off >>= 1) s += __shfl_xor(s, off);
        if (lane == 0) out[(2 * p + j) * 2 + o] = s + fc_b[o];
    }
}

extern "C" void kernel_launch(void* const* d_in, const int* in_sizes, int n_in,
                              void* d_out, int out_size, void* d_ws, size_t ws_size,
                              hipStream_t stream) {
    const float* input = (const float*)d_in[0];
    const int*   knn[5];
    const float* w[5];
    const float* bias[5];
    for (int i = 0; i < 5; ++i) {
        knn[i]  = (const int*)  d_in[1 + 3 * i];
        w[i]    = (const float*)d_in[2 + 3 * i];
        bias[i] = (const float*)d_in[3 + 3 * i];
    }
    const float* fc_w = (const float*)d_in[16];
    const float* fc_b = (const float*)d_in[17];
    float* out = (float*)d_out;

    uint2*    tile = (uint2*)d_ws;                              // 1.48 MB
    unsigned* y0   = (unsigned*)((char*)d_ws + (size_t)OTOT * 8); // 3.7 MB (offset is 256B-aligned)

    repack_tiles<<<(OTOT + 255) / 256, 256, 0, stream>>>(
        knn[0], w[0], knn[1], w[1], knn[2], w[2], knn[3], w[3], knn[4], w[4], tile);

    lcn_l0<<<256, 512, 0, stream>>>(input, tile, bias[0], y0);

    lcn_rest<<<128, 1024, 0, stream>>>(y0, tile, bias[1], bias[2], bias[3], bias[4],
                                       fc_w, fc_b, out);
}

// Round 4
// 37.165 us; speedup vs baseline: 2.2173x; 1.0078x over previous
//
#include <hip/hip_runtime.h>

#define NSTEPS 10
#define D_IN   14400
#define BATCH  256
#define KNN_K  25

// layer dims
#define L0D 7200
#define L1D 3600
#define L2D 1800
#define L3D 900
#define L4D 450

// 64-row groups per layer (ceil(dim/64))
#define G0 113
#define G1 57
#define G2 29
#define G3 15
#define G4 8
// uint2 slots per group = 13 pair-pairs * 64 lanes
#define SPG 832
// layer tile offsets (uint2 units)
#define O1 (G0*SPG)            // 94016
#define O2 (O1 + G1*SPG)       // 141440
#define O3 (O2 + G2*SPG)       // 165568
#define O4 (O3 + G3*SPG)       // 178048
#define OTOT (O4 + G4*SPG)     // 184704

#define NPAIR 128
#define NPACK (NPAIR * (D_IN/4))   // pack work items (uint4 each) = 460800

// round-to-nearest-even f32 -> bf16 bits
__device__ __forceinline__ unsigned bf16b(float x) {
    unsigned u = __float_as_uint(x);
    return (u + 0x7fffu + ((u >> 16) & 1u)) >> 16;
}

// one packed pair: u = (bf16_w << 16) | (idx << 2); act word = bf16 b0 | bf16 b1 << 16
__device__ __forceinline__ void gpair(unsigned u, const char* actb, float& s0, float& s1) {
    unsigned av = *(const unsigned*)(actb + (u & 0xffffu));
    float wf = __uint_as_float(u & 0xffff0000u);
    s0 = fmaf(__uint_as_float(av << 16),          wf, s0);
    s1 = fmaf(__uint_as_float(av & 0xffff0000u),  wf, s1);
}

// ---- prep: (A) repack knn+w into lane-major SoA tiles, (B) pack input slice bf16x2 ----
__global__ void prep_kernel(const int* __restrict__ k0, const float* __restrict__ w0,
                            const int* __restrict__ k1, const float* __restrict__ w1,
                            const int* __restrict__ k2, const float* __restrict__ w2,
                            const int* __restrict__ k3, const float* __restrict__ w3,
                            const int* __restrict__ k4, const float* __restrict__ w4,
                            const float* __restrict__ input,
                            uint2* __restrict__ tile, uint4* __restrict__ xpk)
{
    int s = blockIdx.x * 256 + threadIdx.x;
    if (s < OTOT) {
        const int* kp; const float* wp; int dim, t;
        if      (s < O1) { kp = k0; wp = w0; dim = L0D; t = s;      }
        else if (s < O2) { kp = k1; wp = w1; dim = L1D; t = s - O1; }
        else if (s < O3) { kp = k2; wp = w2; dim = L2D; t = s - O2; }
        else if (s < O4) { kp = k3; wp = w3; dim = L3D; t = s - O3; }
        else             { kp = k4; wp = w4; dim = L4D; t = s - O4; }
        int g    = t / SPG;
        int rem  = t - g * SPG;
        int j    = rem >> 6;          // 0..12
        int lane = rem & 63;
        int r    = g * 64 + lane;
        unsigned vx = 0, vy = 0;
        if (r < dim) {
            int e0 = 2 * j, e1 = 2 * j + 1;
            if (e0 < KNN_K) vx = (bf16b(wp[r * KNN_K + e0]) << 16) | ((unsigned)kp[r * KNN_K + e0] << 2);
            if (e1 < KNN_K) vy = (bf16b(wp[r * KNN_K + e1]) << 16) | ((unsigned)kp[r * KNN_K + e1] << 2);
        }
        tile[s] = make_uint2(vx, vy);
        return;
    }
    int t = s - OTOT;
    if (t < NPACK) {
        int p = t / (D_IN / 4);
        int c = t - p * (D_IN / 4);
        const float4 a = *(const float4*)(input + ((size_t)(2 * p)     * NSTEPS + (NSTEPS - 1)) * D_IN + 4 * c);
        const float4 b = *(const float4*)(input + ((size_t)(2 * p + 1) * NSTEPS + (NSTEPS - 1)) * D_IN + 4 * c);
        uint4 wd;
        wd.x = bf16b(a.x) | (bf16b(b.x) << 16);
        wd.y = bf16b(a.y) | (bf16b(b.y) << 16);
        wd.z = bf16b(a.z) | (bf16b(b.z) << 16);
        wd.w = bf16b(a.w) | (bf16b(b.w) << 16);
        xpk[(size_t)p * (D_IN / 4) + c] = wd;
    }
}

// ---- layer 0: 256 blocks = 128 pairs x 2 neuron-halves; packed input staged to LDS ----
__global__ __launch_bounds__(512, 2)
void lcn_l0(const uint4* __restrict__ xpk, const uint2* __restrict__ tile,
            const float* __restrict__ bias0, unsigned* __restrict__ y0)
{
    __shared__ unsigned act[D_IN];          // 57.6 KB -> 2 blocks/CU
    const int tid = threadIdx.x;
    const int p   = blockIdx.x & 127;       // blocks p and p+128 land on same XCD (b%8)
    const int h   = blockIdx.x >> 7;

    const uint4* src = xpk + (size_t)p * (D_IN / 4);
    for (int i = tid; i < D_IN / 4; i += 512)
        *(uint4*)(act + i * 4) = src[i];
    __syncthreads();
    const char* actb = (const char*)act;

    const int rbase = h ? 3584 : 0;         // 3584 = 56 groups: 64-aligned split
    const int rend  = h ? 7200 : 3584;
#pragma unroll
    for (int i = 0; i < 8; ++i) {
        int r = rbase + tid + i * 512;
        if (r < rend) {
            const uint2* tp = tile + (size_t)(r >> 6) * SPG + (r & 63);
            float s0 = bias0[r], s1 = s0;
#pragma unroll
            for (int j = 0; j < 13; ++j) {
                uint2 u = tp[j * 64];       // coalesced 512B per wave
                gpair(u.x, actb, s0, s1);
                gpair(u.y, actb, s0, s1);
            }
            y0[(size_t)p * L0D + r] = bf16b(s0) | (bf16b(s1) << 16);
        }
    }
}

// ---- layer 1: 256 blocks = 128 pairs x 2 neuron-halves; y0 staged to LDS ----
__global__ __launch_bounds__(512, 4)
void lcn_l1(const unsigned* __restrict__ y0, const uint2* __restrict__ tile,
            const float* __restrict__ bias1, unsigned* __restrict__ y1)
{
    __shared__ unsigned act[L0D];           // 28.8 KB
    const int tid = threadIdx.x;
    const int p   = blockIdx.x & 127;
    const int h   = blockIdx.x >> 7;

    const uint4* src = (const uint4*)(y0 + (size_t)p * L0D);
    for (int i = tid; i < L0D / 4; i += 512)
        *(uint4*)(act + i * 4) = src[i];
    __syncthreads();
    const char* actb = (const char*)act;

    const int rbase = h ? 1792 : 0;         // 28-group split
    const int rend  = h ? 3600 : 1792;
#pragma unroll
    for (int i = 0; i < 4; ++i) {
        int r = rbase + tid + i * 512;
        if (r < rend) {
            const uint2* tp = tile + O1 + (size_t)(r >> 6) * SPG + (r & 63);
            float s0 = bias1[r], s1 = s0;
#pragma unroll
            for (int j = 0; j < 13; ++j) {
                uint2 u = tp[j * 64];
                gpair(u.x, actb, s0, s1);
                gpair(u.y, actb, s0, s1);
            }
            y1[(size_t)p * L1D + r] = bf16b(s0) | (bf16b(s1) << 16);
        }
    }
}

// ---- one deep layer: gather from act[0:prev), reg-stage, write back in place ----
template<int DIM>
__device__ __forceinline__ void k2_layer(unsigned* act, const uint2* tile,
                                         const float* __restrict__ bias, int tid)
{
    constexpr int NI = (DIM + 1023) / 1024;
    float s0[NI], s1[NI];
    const char* actb = (const char*)act;
#pragma unroll
    for (int i = 0; i < NI; ++i) {
        int r = tid + i * 1024;
        if (r < DIM) {
            const uint2* tp = tile + (size_t)(r >> 6) * SPG + (r & 63);
            float a = bias[r], b = a;
#pragma unroll
            for (int j = 0; j < 13; ++j) {
                uint2 u = tp[j * 64];
                gpair(u.x, actb, a, b);
                gpair(u.y, actb, a, b);
            }
            s0[i] = a; s1[i] = b;
        }
    }
    __syncthreads();
#pragma unroll
    for (int i = 0; i < NI; ++i) {
        int r = tid + i * 1024;
        if (r < DIM) act[r] = bf16b(s0[i]) | (bf16b(s1[i]) << 16);
    }
    __syncthreads();
}

// ---- layers 2-4 + fc head: 128 blocks (one per pair), 1024 threads ----
__global__ __launch_bounds__(1024, 4)
void lcn_rest(const unsigned* __restrict__ y1, const uint2* __restrict__ tile,
              const float* __restrict__ bias2, const float* __restrict__ bias3,
              const float* __restrict__ bias4,
              const float* __restrict__ fc_w,  const float* __restrict__ fc_b,
              float* __restrict__ out)
{
    __shared__ unsigned act[L1D];           // 14.4 KB
    const int tid = threadIdx.x;
    const int p   = blockIdx.x;

    const uint4* src = (const uint4*)(y1 + (size_t)p * L1D);
    if (tid < L1D / 4) *(uint4*)(act + tid * 4) = src[tid];
    __syncthreads();

    k2_layer<L2D>(act, tile + O2, bias2, tid);
    k2_layer<L3D>(act, tile + O3, bias3, tid);
    k2_layer<L4D>(act, tile + O4, bias4, tid);

    // fc head: 4 waves handle (batch j, out o)
    const int wv = tid >> 6, lane = tid & 63;
    if (wv < 4) {
        const int j = wv & 1, o = wv >> 1;
        float s = 0.f;
#pragma unroll
        for (int it = 0; it < 8; ++it) {
            int r = lane + it * 64;
            if (r < L4D) {
                unsigned av = act[r];
                float xv = j ? __uint_as_float(av & 0xffff0000u)
                             : __uint_as_float(av << 16);
                s += xv * fc_w[o * L4D + r];
            }
        }
#pragma unroll
        for (int off = 32; off > 0; off >>= 1) s += __shfl_xor(s, off);
        if (lane == 0) out[(2 * p + j) * 2 + o] = s + fc_b[o];
    }
}

extern "C" void kernel_launch(void* const* d_in, const int* in_sizes, int n_in,
                              void* d_out, int out_size, void* d_ws, size_t ws_size,
                              hipStream_t stream) {
    const float* input = (const float*)d_in[0];
    const int*   knn[5];
    const float* w[5];
    const float* bias[5];
    for (int i = 0; i < 5; ++i) {
        knn[i]  = (const int*)  d_in[1 + 3 * i];
        w[i]    = (const float*)d_in[2 + 3 * i];
        bias[i] = (const float*)d_in[3 + 3 * i];
    }
    const float* fc_w = (const float*)d_in[16];
    const float* fc_b = (const float*)d_in[17];
    float* out = (float*)d_out;

    // ws layout (16B-aligned segments)
    char* base = (char*)d_ws;
    uint2*    tile = (uint2*)   base;                          // 1.478 MB
    uint4*    xpk  = (uint4*)  (base + (size_t)OTOT * 8);      // 7.373 MB
    unsigned* y0   = (unsigned*)(base + (size_t)OTOT * 8 + (size_t)NPAIR * D_IN * 4);       // 3.686 MB
    unsigned* y1   = (unsigned*)(base + (size_t)OTOT * 8 + (size_t)NPAIR * D_IN * 4
                                      + (size_t)NPAIR * L0D * 4);                           // 1.843 MB

    const int nprep = OTOT + NPACK;
    prep_kernel<<<(nprep + 255) / 256, 256, 0, stream>>>(
        knn[0], w[0], knn[1], w[1], knn[2], w[2], knn[3], w[3], knn[4], w[4],
        input, tile, xpk);

    lcn_l0<<<256, 512, 0, stream>>>(xpk, tile, bias[0], y0);
    lcn_l1<<<256, 512, 0, stream>>>(y0, tile, bias[1], y1);
    lcn_rest<<<128, 1024, 0, stream>>>(y1, tile, bias[2], bias[3], bias[4],
                                       fc_w, fc_b, out);
}